// Round 1
// baseline (1147.086 us; speedup 1.0000x reference)
//
#include <hip/hip_runtime.h>
#include <float.h>

// MAM dense, fused. C[m,n] = max_k(A[m,k]*W[n,k]) + min_k + bias[n] + arg
// indices (numpy first-occurrence).
//
//  - Main pass: 64x64 tile, 4x4/thread. Products via v_pk_mul_f32 (VOP3P
//    packed fp32, op_sel-broadcast of the W scalar -> 2 products/inst, zero
//    packing movs) + v_max3/v_min3 => 3 VALU per 2 products (was 4).
//  - Chunk-of-last-change tracking (BK=32 windows) as before.
//  - Targets parked in GLOBAL (out_ax/out_an slots hold vmax/vmin until the
//    rescan overwrites them with indices). Drops the 32KB tgt LDS array:
//    LDS 68KB -> ~35KB => 4 blocks/CU by LDS (was 2). __syncthreads orders
//    the intra-block global round-trip (same CU, write-through L1).
//  - Staging transpose-writes XOR-swizzled: row' = row ^ ((k>>2)<<3).
//    Bijective per k-column; read side XORs the b128 group base the same way
//    (contiguity of the 4-row group preserved). 4-way write conflict -> 2-way
//    (free on 32-bank LDS).
//  - Both passes software-pipelined: global->reg prefetch of chunk ch+1
//    issued right after the first barrier, consumed by next iteration's LDS
//    write. Hides HBM/L2 latency under compute.
//  - Rescan: entries bucketed by chunk (LDS atomics + prefix). Per chunk:
//    re-stage the 32-k slice ROW-MAJOR [row][36] (144B stride), scan
//    DESCENDING k with pos=(a*w==t)?k:pos — last write wins = smallest k =
//    first occurrence; products bitwise-match the pk_mul main pass.

typedef float f32x2 __attribute__((ext_vector_type(2)));
typedef float f32x4 __attribute__((ext_vector_type(4)));

#define BM 64
#define BN 64
#define BK 32
#define LDP 68    // main staging [BK][LDP], +4 pad
#define LDP2 36   // rescan row-major [64][LDP2]; 144B stride
#define NCHUNK 32
#define NENT (BM * BN * 2)

// D.lo = S0.lo * S1.lo ; D.hi = S0.hi * S1.lo   (broadcast S1 low half)
__device__ __forceinline__ f32x2 pk_mul_blo(f32x2 a, f32x2 w) {
  f32x2 d;
  asm("v_pk_mul_f32 %0, %1, %2 op_sel:[0,0] op_sel_hi:[1,0]"
      : "=v"(d) : "v"(a), "v"(w));
  return d;
}
// D.lo = S0.lo * S1.hi ; D.hi = S0.hi * S1.hi   (broadcast S1 high half)
__device__ __forceinline__ f32x2 pk_mul_bhi(f32x2 a, f32x2 w) {
  f32x2 d;
  asm("v_pk_mul_f32 %0, %1, %2 op_sel:[0,1] op_sel_hi:[1,1]"
      : "=v"(d) : "v"(a), "v"(w));
  return d;
}

__global__ __launch_bounds__(256, 3)
void mam_fused(const float* __restrict__ A, const float* __restrict__ W,
               const float* __restrict__ bias,
               float* __restrict__ out_v, float* __restrict__ out_ax,
               float* __restrict__ out_an, int M, int N, int K) {
  // aliased staging pool, sized for the larger (rescan) layout:
  //   main:   Als[32][68] @0 (8704B) + Wls[32][68] @8704 (ends 17408B)
  //   rescan: As2[64][36] @0 (9216B) + Ws2[64][36] @9216 (ends 18432B)
  __shared__ __align__(16) unsigned char pool[2 * 64 * LDP2 * 4];
  float(*Als)[LDP] = (float(*)[LDP])pool;
  float(*Wls)[LDP] = (float(*)[LDP])(pool + BK * LDP * 4);
  float(*As2)[LDP2] = (float(*)[LDP2])pool;
  float(*Ws2)[LDP2] = (float(*)[LDP2])(pool + 64 * LDP2 * 4);
  __shared__ unsigned short ents[NENT];
  __shared__ unsigned cnt[NCHUNK];
  __shared__ unsigned off[NCHUNK + 1];

  const int tid = threadIdx.x;
  const int tx = tid & 15;
  const int ty = tid >> 4;
  const int m0 = blockIdx.y * BM;
  const int n0 = blockIdx.x * BN;

  float vmax[4][4], vmin[4][4];
  int cmax[4][4], cmin[4][4];
#pragma unroll
  for (int i = 0; i < 4; ++i)
#pragma unroll
    for (int j = 0; j < 4; ++j) {
      vmax[i][j] = -FLT_MAX;
      vmin[i][j] = FLT_MAX;
      cmax[i][j] = 0;
      cmin[i][j] = 0;
    }

  const int r = tid >> 3;  // 0..31
  const int c8 = tid & 7;  // 0..7
  const int kcol = c8 * 4;
  const int row0s = r ^ (c8 << 3);         // swizzled staging rows
  const int row1s = (r + 32) ^ (c8 << 3);

  // clamped global row pointers (computed once)
  int gmA0 = m0 + r;      gmA0 = gmA0 < M ? gmA0 : M - 1;
  int gmA1 = m0 + r + 32; gmA1 = gmA1 < M ? gmA1 : M - 1;
  int gnW0 = n0 + r;      gnW0 = gnW0 < N ? gnW0 : N - 1;
  int gnW1 = n0 + r + 32; gnW1 = gnW1 < N ? gnW1 : N - 1;
  const float* pA0 = A + (size_t)gmA0 * K + kcol;
  const float* pA1 = A + (size_t)gmA1 * K + kcol;
  const float* pW0 = W + (size_t)gnW0 * K + kcol;
  const float* pW1 = W + (size_t)gnW1 * K + kcol;

  const int nchunk = K / BK;

  // prologue prefetch: chunk 0
  f32x4 fa0 = *(const f32x4*)(pA0);
  f32x4 fa1 = *(const f32x4*)(pA1);
  f32x4 fw0 = *(const f32x4*)(pW0);
  f32x4 fw1 = *(const f32x4*)(pW1);

  const int ty4 = ty * 4, tx4 = tx * 4;

  for (int ch = 0; ch < nchunk; ++ch) {
    // stage prefetched regs -> LDS (transpose, swizzled rows: 2-way banks)
    Als[kcol + 0][row0s] = fa0.x; Als[kcol + 1][row0s] = fa0.y;
    Als[kcol + 2][row0s] = fa0.z; Als[kcol + 3][row0s] = fa0.w;
    Als[kcol + 0][row1s] = fa1.x; Als[kcol + 1][row1s] = fa1.y;
    Als[kcol + 2][row1s] = fa1.z; Als[kcol + 3][row1s] = fa1.w;
    Wls[kcol + 0][row0s] = fw0.x; Wls[kcol + 1][row0s] = fw0.y;
    Wls[kcol + 2][row0s] = fw0.z; Wls[kcol + 3][row0s] = fw0.w;
    Wls[kcol + 0][row1s] = fw1.x; Wls[kcol + 1][row1s] = fw1.y;
    Wls[kcol + 2][row1s] = fw1.z; Wls[kcol + 3][row1s] = fw1.w;
    __syncthreads();

    // issue next chunk's loads; results consumed at next LDS-stage
    if (ch + 1 < nchunk) {
      const int koff = (ch + 1) * BK;
      fa0 = *(const f32x4*)(pA0 + koff);
      fa1 = *(const f32x4*)(pA1 + koff);
      fw0 = *(const f32x4*)(pW0 + koff);
      fw1 = *(const f32x4*)(pW1 + koff);
    }

    float tmax[4][4], tmin[4][4];
#pragma unroll
    for (int i = 0; i < 4; ++i)
#pragma unroll
      for (int j = 0; j < 4; ++j) { tmax[i][j] = -FLT_MAX; tmin[i][j] = FLT_MAX; }

#pragma unroll
    for (int k = 0; k < BK; k += 2) {
      const int swz = (k >> 2) << 3;  // matches staging swizzle (k,k+1 share)
      const f32x4 av0 = *(const f32x4*)(&Als[k][ty4 ^ swz]);
      const f32x4 av1 = *(const f32x4*)(&Als[k + 1][ty4 ^ swz]);
      const f32x4 wv0 = *(const f32x4*)(&Wls[k][tx4 ^ swz]);
      const f32x4 wv1 = *(const f32x4*)(&Wls[k + 1][tx4 ^ swz]);
#pragma unroll
      for (int jh = 0; jh < 2; ++jh) {
        const f32x2 w0p = jh ? wv0.zw : wv0.xy;
        const f32x2 w1p = jh ? wv1.zw : wv1.xy;
        {  // j = 2*jh : broadcast low half of the W pair
          const int j = 2 * jh;
          const f32x2 q00 = pk_mul_blo(av0.xy, w0p);  // k,   rows i0,i1
          const f32x2 q01 = pk_mul_blo(av0.zw, w0p);  // k,   rows i2,i3
          const f32x2 q10 = pk_mul_blo(av1.xy, w1p);  // k+1, rows i0,i1
          const f32x2 q11 = pk_mul_blo(av1.zw, w1p);  // k+1, rows i2,i3
          tmax[0][j] = fmaxf(tmax[0][j], fmaxf(q00.x, q10.x));  // v_max3_f32
          tmin[0][j] = fminf(tmin[0][j], fminf(q00.x, q10.x));  // v_min3_f32
          tmax[1][j] = fmaxf(tmax[1][j], fmaxf(q00.y, q10.y));
          tmin[1][j] = fminf(tmin[1][j], fminf(q00.y, q10.y));
          tmax[2][j] = fmaxf(tmax[2][j], fmaxf(q01.x, q11.x));
          tmin[2][j] = fminf(tmin[2][j], fminf(q01.x, q11.x));
          tmax[3][j] = fmaxf(tmax[3][j], fmaxf(q01.y, q11.y));
          tmin[3][j] = fminf(tmin[3][j], fminf(q01.y, q11.y));
        }
        {  // j = 2*jh+1 : broadcast high half of the W pair
          const int j = 2 * jh + 1;
          const f32x2 q00 = pk_mul_bhi(av0.xy, w0p);
          const f32x2 q01 = pk_mul_bhi(av0.zw, w0p);
          const f32x2 q10 = pk_mul_bhi(av1.xy, w1p);
          const f32x2 q11 = pk_mul_bhi(av1.zw, w1p);
          tmax[0][j] = fmaxf(tmax[0][j], fmaxf(q00.x, q10.x));
          tmin[0][j] = fminf(tmin[0][j], fminf(q00.x, q10.x));
          tmax[1][j] = fmaxf(tmax[1][j], fmaxf(q00.y, q10.y));
          tmin[1][j] = fminf(tmin[1][j], fminf(q00.y, q10.y));
          tmax[2][j] = fmaxf(tmax[2][j], fmaxf(q01.x, q11.x));
          tmin[2][j] = fminf(tmin[2][j], fminf(q01.x, q11.x));
          tmax[3][j] = fmaxf(tmax[3][j], fmaxf(q01.y, q11.y));
          tmin[3][j] = fminf(tmin[3][j], fminf(q01.y, q11.y));
        }
      }
    }

#pragma unroll
    for (int i = 0; i < 4; ++i)
#pragma unroll
      for (int j = 0; j < 4; ++j) {
        if (tmax[i][j] > vmax[i][j]) { vmax[i][j] = tmax[i][j]; cmax[i][j] = ch; }
        if (tmin[i][j] < vmin[i][j]) { vmin[i][j] = tmin[i][j]; cmin[i][j] = ch; }
      }
    __syncthreads();
  }

  // ---- rescan prefetch issued early (hides under epilogue + bucketing) ----
  const int row2 = tid >> 2;  // 0..63
  const int q2 = tid & 3;     // 0..3
  int gmr = m0 + row2; gmr = gmr < M ? gmr : M - 1;
  int gnr = n0 + row2; gnr = gnr < N ? gnr : N - 1;
  const float* pAr = A + (size_t)gmr * K + q2 * 4;
  const float* pWr = W + (size_t)gnr * K + q2 * 4;
  f32x4 ra0 = *(const f32x4*)(pAr);
  f32x4 ra1 = *(const f32x4*)(pAr + 16);
  f32x4 rw0 = *(const f32x4*)(pWr);
  f32x4 rw1 = *(const f32x4*)(pWr + 16);

  // ---- value output + park targets in their OWN output slots ----
  const size_t MN = (size_t)M * N;
  const int gn = n0 + tx4;
  f32x4 bv = {0.f, 0.f, 0.f, 0.f};
  if (gn + 3 < N) bv = *(const f32x4*)(bias + gn);
#pragma unroll
  for (int i = 0; i < 4; ++i) {
    const int gm = m0 + ty4 + i;
    if (gm < M && gn + 3 < N) {
      const size_t base = (size_t)gm * N + gn;
      const f32x4 vx = {vmax[i][0], vmax[i][1], vmax[i][2], vmax[i][3]};
      const f32x4 vn = {vmin[i][0], vmin[i][1], vmin[i][2], vmin[i][3]};
      *(f32x4*)(out_v + base) = vx + vn + bv;
      *(f32x4*)(out_ax + base) = vx;  // target, overwritten with index below
      *(f32x4*)(out_an + base) = vn;  // target, overwritten with index below
    }
  }

  // ---- bucket entries by chunk (side rides in the entry) ----
  if (tid < NCHUNK) cnt[tid] = 0;
  __syncthreads();
#pragma unroll
  for (int i = 0; i < 4; ++i)
#pragma unroll
    for (int j = 0; j < 4; ++j) {
      atomicAdd(&cnt[cmax[i][j]], 1u);
      atomicAdd(&cnt[cmin[i][j]], 1u);
    }
  __syncthreads();
  if (tid == 0) {
    unsigned s = 0;
    for (int b = 0; b < NCHUNK; ++b) { off[b] = s; s += cnt[b]; }
    off[NCHUNK] = s;
  }
  __syncthreads();
  if (tid < NCHUNK) cnt[tid] = off[tid];
  __syncthreads();
#pragma unroll
  for (int i = 0; i < 4; ++i)
#pragma unroll
    for (int j = 0; j < 4; ++j) {
      const unsigned enc = (unsigned)((ty4 + i) * 64 + (tx4 + j));
      unsigned p1 = atomicAdd(&cnt[cmax[i][j]], 1u);
      ents[p1] = (unsigned short)enc;               // side 0
      unsigned p2 = atomicAdd(&cnt[cmin[i][j]], 1u);
      ents[p2] = (unsigned short)(enc | 0x1000u);   // side 1
    }

  // ---- per-chunk rescan: first k with product == target ----
  for (int ch = 0; ch < nchunk; ++ch) {
    const int kk = ch * BK;
    __syncthreads();  // prior readers (and bucketing/epilogue) done
    *(f32x4*)(&As2[row2][q2 * 4]) = ra0;
    *(f32x4*)(&As2[row2][q2 * 4 + 16]) = ra1;
    *(f32x4*)(&Ws2[row2][q2 * 4]) = rw0;
    *(f32x4*)(&Ws2[row2][q2 * 4 + 16]) = rw1;
    if (ch + 1 < nchunk) {
      const int koff = (ch + 1) * BK;
      ra0 = *(const f32x4*)(pAr + koff);
      ra1 = *(const f32x4*)(pAr + koff + 16);
      rw0 = *(const f32x4*)(pWr + koff);
      rw1 = *(const f32x4*)(pWr + koff + 16);
    }
    __syncthreads();

    const int lo = off[ch], hi = off[ch + 1];
    for (int e = lo + tid; e < hi; e += 256) {
      const int enc = ents[e];
      const int side = enc >> 12;
      const int ml = (enc >> 6) & 63;
      const int nl = enc & 63;
      const int gm = m0 + ml, gnn = n0 + nl;
      if (gm < M && gnn < N) {
        float* slot = out_ax + (size_t)side * MN + (size_t)gm * N + gnn;
        const float t = *slot;  // parked target (L1/L2 hit)
        unsigned pos = 0;
#pragma unroll
        for (int g = 7; g >= 0; --g) {  // descending k: last write = min k
          const f32x4 a4 = *(const f32x4*)(&As2[ml][g * 4]);
          const f32x4 w4 = *(const f32x4*)(&Ws2[nl][g * 4]);
          pos = (a4.w * w4.w == t) ? (unsigned)(g * 4 + 3) : pos;
          pos = (a4.z * w4.z == t) ? (unsigned)(g * 4 + 2) : pos;
          pos = (a4.y * w4.y == t) ? (unsigned)(g * 4 + 1) : pos;
          pos = (a4.x * w4.x == t) ? (unsigned)(g * 4 + 0) : pos;
        }
        *slot = (float)(kk + (int)pos);
      }
    }
  }
}

extern "C" void kernel_launch(void* const* d_in, const int* in_sizes, int n_in,
                              void* d_out, int out_size, void* d_ws, size_t ws_size,
                              hipStream_t stream) {
  const float* A = (const float*)d_in[0];     // [M, K] fp32
  const float* W = (const float*)d_in[1];     // [N, K] fp32
  const float* bias = (const float*)d_in[2];  // [N]    fp32
  const int N = in_sizes[2];
  const int K = in_sizes[1] / N;
  const int M = in_sizes[0] / K;
  float* out_v = (float*)d_out;
  float* out_ax = out_v + (size_t)M * N;
  float* out_an = out_v + 2 * (size_t)M * N;
  dim3 grid((N + BN - 1) / BN, (M + BM - 1) / BM);
  mam_fused<<<grid, dim3(256), 0, stream>>>(A, W, bias, out_v, out_ax, out_an,
                                            M, N, K);
}